// Round 16
// baseline (62.914 us; speedup 1.0000x reference)
//
#include <hip/hip_runtime.h>
#include <math.h>

// Problem geometry
#define T_LEN   160000
#define NROW    128        // 64 rows of x then 64 rows of n
#define CH      32         // stage-1 state chunk (a1/scan/s1)
#define NCH     5000       // CH*NCH == T_LEN
#define OWNT    20         // chunks per thread in scan_row
// emit geometry (16-sample chunks)
#define NCH16   10000
#define OWN16   60         // own 16-chunks per wave (+4 warm = 64)
#define B16     240        // own 16-chunks per block
#define TILES16 42         // ceil(10000/240)
#define NBLK16  (NROW * TILES16)   // 5376
#define ROW4    40000      // float4 per row

// HP biquad: y = x - 2 x1 + x2 + 1.99599 y1 - 0.996 y2
#define C1_HP ( 1.99599)
#define C2_HP (-0.996)
#define C1F   ( 1.99599f)
#define C2F   (-0.996f)

#define S1_FLOAT2S (NROW * NCH)          // 640000 float2 = 5,120,000 B
#define M2_BYTE_OFF (S1_FLOAT2S * 8)     // 16B-aligned

#define GLOBAL_AS __attribute__((address_space(1)))
#define SHARED_AS __attribute__((address_space(3)))

// INVOLUTIVE swizzle (bits 3,4,5 -> XOR into 0,1,2; disjoint => sz(sz(F))=F).
// Required by the async global_load_lds path: it writes ws4[k]=src4[sz(k)],
// which matches the manual layout ws4[sz(f)]=src4[f] iff sz is an involution.
__device__ __forceinline__ int sz16(int F) { return F ^ ((F >> 3) & 7); }
__device__ __forceinline__ float clip1f(float v) { return fminf(fmaxf(v, -1.0f), 1.0f); }

// ---------------------------------------------------------------------------
// pass_a1: per (row, 32-chunk) LOCAL stage-1 end state (zero y-init, true
// x-history). FIR f32, y-recurrence f64; e1 stored f32.
// Threads g<2 also emit M16 = A2stage^16 and its powers M^2, M^3 per filter.
// ---------------------------------------------------------------------------
__global__ __launch_bounds__(256) void pass_a1(const float* __restrict__ x,
                                               const float* __restrict__ nn,
                                               float2* __restrict__ e1,
                                               const float* __restrict__ cx,
                                               const float* __restrict__ cn,
                                               float4* __restrict__ m2) {
  int g = blockIdx.x * blockDim.x + threadIdx.x;
  if (g < 2) {                       // folded prep: M16 powers
    const float* c = g ? cn : cx;
    const float A1c = c[0], A2c = c[1];
    float pm2 = 0.f, pm1 = 0.f, p0 = 1.f;
#pragma unroll
    for (int k = 0; k < 16; ++k) {
      float pn = -A1c * p0 - A2c * pm1;
      pm2 = pm1; pm1 = p0; p0 = pn;
    }
    float m00 = p0, m01 = -A2c * pm1, m10 = pm1, m11 = -A2c * pm2;
    float q00 = m00*m00 + m01*m10, q01 = m00*m01 + m01*m11;
    float q10 = m10*m00 + m11*m10, q11 = m10*m01 + m11*m11;       // M^2
    float r00 = q00*m00 + q01*m10, r01 = q00*m01 + q01*m11;
    float r10 = q10*m00 + q11*m10, r11 = q10*m01 + q11*m11;       // M^3
    m2[g*3 + 0] = make_float4(m00, m01, m10, m11);
    m2[g*3 + 1] = make_float4(q00, q01, q10, q11);
    m2[g*3 + 2] = make_float4(r00, r01, r10, r11);
  }
  if (g >= NROW * NCH) return;
  int row = g / NCH, c = g % NCH;
  const float* src = (row < 64) ? (x + (size_t)row * T_LEN)
                                : (nn + (size_t)(row - 64) * T_LEN);
  const float* xp = src + c * CH;
  float x1 = 0.f, x2 = 0.f;
  if (c) { x1 = xp[-1]; x2 = xp[-2]; }
  double y1 = 0.0, y2 = 0.0;
#pragma unroll
  for (int j = 0; j < CH; j += 4) {
    float4 xv = *reinterpret_cast<const float4*>(xp + j);
#define A1STEP(XF) { float xt = (XF); \
    float fir = (xt - 2.f * x1 + x2); \
    double y = fma(C1_HP, y1, fma(C2_HP, y2, (double)fir)); \
    x2 = x1; x1 = xt; y2 = y1; y1 = y; }
    A1STEP(xv.x) A1STEP(xv.y) A1STEP(xv.z) A1STEP(xv.w)
#undef A1STEP
  }
  e1[g] = make_float2((float)y1, (float)y2);
}

// ---------------------------------------------------------------------------
// scan_row: one block (4 waves) per row; affine Kogge-Stone over 32-chunk
// maps (f64 internal, f32 e-inputs); emits exact chunk-start states (f32).
// ---------------------------------------------------------------------------
__global__ __launch_bounds__(256) void scan_row(const float2* __restrict__ e,
                                                float2* __restrict__ s) {
  __shared__ double wm[4][6];
  const int t = threadIdx.x, row = blockIdx.x;
  const int lane = t & 63, wv = t >> 6;
  double pm2 = 0.0, pm1 = 0.0, p0 = 1.0;
#pragma unroll
  for (int k = 1; k <= CH; ++k) {
    double pn = C1_HP * p0 + C2_HP * pm1;
    pm2 = pm1; pm1 = p0; p0 = pn;
  }
  const double m00 = p0,  m01 = C2_HP * pm1;
  const double m10 = pm1, m11 = C2_HP * pm2;
  const float2* ep = e + (size_t)row * NCH;
  const int base = t * OWNT;
  double f1 = 0.0, f2 = 0.0;
  for (int j = 0; j < OWNT; ++j) {
    int c = base + j;
    float2 ev = (c < NCH) ? ep[c] : make_float2(0.f, 0.f);
    double n1 = m00 * f1 + m01 * f2 + (double)ev.x;
    double n2 = m10 * f1 + m11 * f2 + (double)ev.y;
    f1 = n1; f2 = n2;
  }
  double b00 = m00, b01 = m01, b10 = m10, b11 = m11;
  double r00 = 1.0, r01 = 0.0, r10 = 0.0, r11 = 1.0;
  int ee = OWNT;
  while (ee) {
    if (ee & 1) {
      double t00 = b00 * r00 + b01 * r10, t01 = b00 * r01 + b01 * r11;
      double t10 = b10 * r00 + b11 * r10, t11 = b10 * r01 + b11 * r11;
      r00 = t00; r01 = t01; r10 = t10; r11 = t11;
    }
    double q00 = b00 * b00 + b01 * b10, q01 = b00 * b01 + b01 * b11;
    double q10 = b10 * b00 + b11 * b10, q11 = b10 * b01 + b11 * b11;
    b00 = q00; b01 = q01; b10 = q10; b11 = q11;
    ee >>= 1;
  }
  double P00 = r00, P01 = r01, P10 = r10, P11 = r11, V1 = f1, V2 = f2;
#pragma unroll
  for (int off = 1; off < 64; off <<= 1) {
    double u00 = __shfl_up(P00, off), u01 = __shfl_up(P01, off);
    double u10 = __shfl_up(P10, off), u11 = __shfl_up(P11, off);
    double uv1 = __shfl_up(V1, off),  uv2 = __shfl_up(V2, off);
    if (lane >= off) {
      double nv1 = P00 * uv1 + P01 * uv2 + V1;
      double nv2 = P10 * uv1 + P11 * uv2 + V2;
      double n00 = P00 * u00 + P01 * u10, n01 = P00 * u01 + P01 * u11;
      double n10 = P10 * u00 + P11 * u10, n11 = P10 * u01 + P11 * u11;
      P00 = n00; P01 = n01; P10 = n10; P11 = n11; V1 = nv1; V2 = nv2;
    }
  }
  if (lane == 63) {
    wm[wv][0] = P00; wm[wv][1] = P01; wm[wv][2] = P10; wm[wv][3] = P11;
    wm[wv][4] = V1;  wm[wv][5] = V2;
  }
  __syncthreads();
  double S1 = 0.0, S2 = 0.0;
  for (int w = 0; w < wv; ++w) {
    double n1 = wm[w][0] * S1 + wm[w][1] * S2 + wm[w][4];
    double n2 = wm[w][2] * S1 + wm[w][3] * S2 + wm[w][5];
    S1 = n1; S2 = n2;
  }
  double q00 = __shfl_up(P00, 1), q01 = __shfl_up(P01, 1);
  double q10 = __shfl_up(P10, 1), q11 = __shfl_up(P11, 1);
  double qv1 = __shfl_up(V1, 1),  qv2 = __shfl_up(V2, 1);
  double st1, st2;
  if (lane == 0) { st1 = S1; st2 = S2; }
  else { st1 = q00 * S1 + q01 * S2 + qv1; st2 = q10 * S1 + q11 * S2 + qv2; }
  float2* sp = s + (size_t)row * NCH;
  double s1v = st1, s2v = st2;
  for (int j = 0; j < OWNT; ++j) {
    int c = base + j;
    if (c < NCH) {
      sp[c] = make_float2((float)s1v, (float)s2v);
      float2 ev = ep[c];
      double n1 = m00 * s1v + m01 * s2v + (double)ev.x;
      double n2 = m10 * s1v + m11 * s2v + (double)ev.y;
      s1v = n1; s2v = n2;
    }
  }
}

// ---------------------------------------------------------------------------
// emit: 16-sample chunks, 4 KB/wave tile -> 32 waves/CU. Lane owns one
// 16-chunk (4 warm lanes + 60 own). Even lanes seed stage-1 from s1_32
// directly; odd lanes advance the exact seed 16 steps (pred chunk from LDS).
// Zero-z AB per chunk; s2 = e2[c-1] + M*e2[c-2] + M^2*e2[c-3] + M^3*e2[c-4]
// via shfl_up; homogeneous correction + clip; LDS write-back; coalesced store.
// ZERO barriers (all exchange wave-local).
// ---------------------------------------------------------------------------
__global__ __launch_bounds__(256, 8) void emit_kernel(const float* __restrict__ x,
                                                      const float* __restrict__ nn,
                                                      const float2* __restrict__ s1,
                                                      const float* __restrict__ cx,
                                                      const float* __restrict__ cn,
                                                      const float4* __restrict__ m2,
                                                      float* __restrict__ out) {
  __shared__ float4 ws4[1024];                 // 4 waves x 256 float4 = 16 KB
  const int tid = threadIdx.x, lane = tid & 63, wv = tid >> 6;
  const int b = blockIdx.x;
  const int row = b / TILES16, tile = b % TILES16;
  const int W0 = tile * B16 + wv * OWN16;      // first own 16-chunk (even)
  const int c = W0 - 4 + lane;                 // lane's 16-chunk
  const float* src = (row < 64) ? x + (size_t)row * T_LEN
                                : nn + (size_t)(row - 64) * T_LEN;
  const float4* src4 = reinterpret_cast<const float4*>(src);
  const float2* srow = s1 + (size_t)row * NCH;
  const float* cf = (row < 64) ? cx : cn;
  const float A1c = cf[0], A2c = cf[1], B1c = cf[2], B2c = cf[3];
  const int fi = (row < 64) ? 0 : 1;
  const float4 M1q = m2[fi*3], M2q = m2[fi*3+1], M3q = m2[fi*3+2];
  const bool cOK = (c >= 0) && (c < NCH16);

  const int WOFF = wv * 256;
  const long base4 = (long)(W0 - 4) * 4;       // float4 idx of tile start
  const bool interior = (base4 >= 0) && (base4 + 256 <= ROW4);

  if (interior) {
    // async staging: LDS linear, involutive swizzle folded into global src.
    // sz16(q*64+l) = q*64 + (l ^ ((l>>3)&7)) since q*8 % 8 == 0.
    const int lane_sz = lane ^ ((lane >> 3) & 7);
#pragma unroll
    for (int q = 0; q < 4; ++q) {
      const float4* gp = src4 + base4 + q * 64 + lane_sz;
      __builtin_amdgcn_global_load_lds(
          (const GLOBAL_AS void*)gp,
          (SHARED_AS void*)(ws4 + WOFF + q * 64),
          16, 0, 0);
    }
    asm volatile("s_waitcnt vmcnt(0)" ::: "memory");
  } else {
#pragma unroll
    for (int q = 0; q < 4; ++q) {
      int f = q * 64 + lane;
      long g4 = base4 + f;
      float4 v = make_float4(0.f, 0.f, 0.f, 0.f);
      if (g4 >= 0 && g4 < ROW4) v = src4[g4];
      ws4[WOFF + sz16(f)] = v;
    }
  }

  float4 a[4];
#pragma unroll
  for (int q = 0; q < 4; ++q) a[q] = ws4[WOFF + sz16(lane * 4 + q)];

  // tails of predecessor chunks (before any overwrite)
  float tx  = __shfl_up(a[3].w, 1), ty  = __shfl_up(a[3].z, 1);
  float t2x = __shfl_up(a[3].w, 2), t2y = __shfl_up(a[3].z, 2);

  float x1 = 0.f, x2 = 0.f, y1 = 0.f, y2 = 0.f, v1 = 0.f, v2 = 0.f;
  if (cOK && c > 0) {
    float2 sv = srow[c >> 1];                  // exact state (f64-scan) at
    y1 = sv.x; y2 = sv.y;                      // sample 32*(c>>1)
    if ((lane & 1) == 0) {                     // even chunk: direct seed
      if (lane == 0) {
        float2 tp = *reinterpret_cast<const float2*>(src + (long)c * 16 - 2);
        x2 = tp.x; x1 = tp.y;
      } else { x1 = tx; x2 = ty; }
    } else {                                   // odd chunk: advance 16 steps
      float ax1 = 0.f, ax2 = 0.f;
      if (lane == 1) {
        if (c >= 2) {
          float2 tp = *reinterpret_cast<const float2*>(src + (long)(c - 1) * 16 - 2);
          ax2 = tp.x; ax1 = tp.y;
        }
      } else { ax1 = t2x; ax2 = t2y; }
      float4 p0 = ws4[WOFF + sz16((lane - 1) * 4 + 0)];
      float4 p1 = ws4[WOFF + sz16((lane - 1) * 4 + 1)];
      float4 p2 = ws4[WOFF + sz16((lane - 1) * 4 + 2)];
      float4 p3 = ws4[WOFF + sz16((lane - 1) * 4 + 3)];
#define ADV(XT) { float xt_ = (XT); \
      float fir = (xt_ - 2.f * ax1 + ax2); \
      float yy = fmaf(C1F, y1, fmaf(C2F, y2, fir)); \
      ax2 = ax1; ax1 = xt_; y2 = y1; y1 = yy; }
      ADV(p0.x) ADV(p0.y) ADV(p0.z) ADV(p0.w)
      ADV(p1.x) ADV(p1.y) ADV(p1.z) ADV(p1.w)
      ADV(p2.x) ADV(p2.y) ADV(p2.z) ADV(p2.w)
      ADV(p3.x) ADV(p3.y) ADV(p3.z) ADV(p3.w)
#undef ADV
      x1 = ax1; x2 = ax2;
    }
    v1 = clip1f(y1); v2 = clip1f(y2);
  }

  // ---- FIR precompute (input-only): a[q] := fir ----
  {
    float xp1 = x1, xp2 = x2;
#pragma unroll
    for (int q = 0; q < 4; ++q) {
      float4 t = a[q];
      float4 f;
      f.x = t.x - 2.f * xp1 + xp2;
      f.y = t.y - 2.f * t.x + xp1;
      f.z = t.z - 2.f * t.y + t.x;
      f.w = t.w - 2.f * t.z + t.y;
      xp2 = t.z; xp1 = t.w;
      a[q] = f;
    }
  }

  // ---- fused stage1 + stage2(zero-z): a[q] := zb ----
  float z1 = 0.f, z2 = 0.f;
  if (cOK) {
#define AB(REF) { \
    float yy = fmaf(C1F, y1, fmaf(C2F, y2, (REF))); \
    float vv = clip1f(yy); \
    float zz = fmaf(-A1c, z1, fmaf(-A2c, z2, fmaf(B2c, v2, fmaf(B1c, v1, vv)))); \
    y2 = y1; y1 = yy; v2 = v1; v1 = vv; z2 = z1; z1 = zz; REF = zz; }
#pragma unroll
    for (int q = 0; q < 4; ++q) { AB(a[q].x) AB(a[q].y) AB(a[q].z) AB(a[q].w) }
#undef AB
  }

  // e2 states of the four previous chunks via shuffles
  float u1x = __shfl_up(z1, 1), u1y = __shfl_up(z2, 1);
  float u2x = __shfl_up(z1, 2), u2y = __shfl_up(z2, 2);
  float u3x = __shfl_up(z1, 3), u3y = __shfl_up(z2, 3);
  float u4x = __shfl_up(z1, 4), u4y = __shfl_up(z2, 4);

  // ---- correction + clip, write back to LDS (own lanes only) ----
  if (lane >= 4 && cOK) {
    float s2x = 0.f, s2y = 0.f;
    if (c >= 1) { s2x = u1x; s2y = u1y; }
    if (c >= 2) { s2x = fmaf(M1q.x, u2x, fmaf(M1q.y, u2y, s2x));
                  s2y = fmaf(M1q.z, u2x, fmaf(M1q.w, u2y, s2y)); }
    if (c >= 3) { s2x = fmaf(M2q.x, u3x, fmaf(M2q.y, u3y, s2x));
                  s2y = fmaf(M2q.z, u3x, fmaf(M2q.w, u3y, s2y)); }
    if (c >= 4) { s2x = fmaf(M3q.x, u4x, fmaf(M3q.y, u4y, s2x));
                  s2y = fmaf(M3q.z, u4x, fmaf(M3q.w, u4y, s2y)); }
    float h1 = s2x, h2 = s2y;
#define CS(ZB, OT) { float hh = fmaf(-A1c, h1, -A2c * h2); \
    OT = clip1f((ZB) + hh); h2 = h1; h1 = hh; }
#pragma unroll
    for (int q = 0; q < 4; ++q) {
      float4 o;
      CS(a[q].x, o.x) CS(a[q].y, o.y) CS(a[q].z, o.z) CS(a[q].w, o.w)
      ws4[WOFF + sz16(lane * 4 + q)] = o;
    }
#undef CS
  }

  // ---- coalesced store of own chunks (f >= 16) from LDS (no barrier) ----
  float* orow = out + (size_t)row * T_LEN;
#pragma unroll
  for (int q = 0; q < 4; ++q) {
    int f = q * 64 + lane;
    long g4 = base4 + f;
    if (f >= 16 && g4 < ROW4)
      reinterpret_cast<float4*>(orow)[g4] = ws4[WOFF + sz16(f)];
  }
}

// ---------------------------------------------------------------------------
extern "C" void kernel_launch(void* const* d_in, const int* in_sizes, int n_in,
                              void* d_out, int out_size, void* d_ws, size_t ws_size,
                              hipStream_t stream) {
  const float* x  = (const float*)d_in[0];   // (64, 160000)
  const float* nn = (const float*)d_in[1];   // (64, 160000)
  const float* cx = (const float*)d_in[2];   // (4,) a1,a2,b1,b2
  const float* cn = (const float*)d_in[3];   // (4,)
  float* out = (float*)d_out;                // (128, 160000) flat

  // e1 (f32, 5.12 MB) aliases d_out: written by pass_a1, consumed by
  // scan_row, then fully overwritten by emit. s1 + m2 (96 B) in ws.
  float2* e1 = (float2*)d_out;
  float2* s1 = (float2*)d_ws;
  float4* m2 = (float4*)((char*)d_ws + M2_BYTE_OFF);

  const int total = NROW * NCH;              // 640000
  const int blk = 256;
  const int nb = (total + blk - 1) / blk;    // 2500

  pass_a1<<<nb, blk, 0, stream>>>(x, nn, e1, cx, cn, m2);
  scan_row<<<NROW, blk, 0, stream>>>(e1, s1);
  emit_kernel<<<NBLK16, blk, 0, stream>>>(x, nn, s1, cx, cn, m2, out);
}

// Round 17
// 61.080 us; speedup vs baseline: 1.0300x; 1.0300x over previous
//
#include <hip/hip_runtime.h>
#include <math.h>

// Problem geometry
#define T_LEN   160000
#define NROW    128        // 64 rows of x then 64 rows of n
#define CH      32         // stage-1 state chunk (a1/scan/s1)
#define NCH     5000       // CH*NCH == T_LEN
#define OWNT    20         // chunks per thread in scan_row
// emit geometry (16-sample chunks, two tiles per wave)
#define NCH16   10000
#define OWN16   60         // own 16-chunks per tile (+4 warm = 64 staged)
#define WAVE_OWN 120       // two tiles per wave
#define B16     480        // own 16-chunks per block (4 waves)
#define TILES16 21         // ceil(10000/480)
#define NBLK16  (NROW * TILES16)   // 2688
#define ROW4    40000      // float4 per row

// HP biquad: y = x - 2 x1 + x2 + 1.99599 y1 - 0.996 y2
#define C1_HP ( 1.99599)
#define C2_HP (-0.996)
#define C1F   ( 1.99599f)
#define C2F   (-0.996f)

#define S1_FLOAT2S (NROW * NCH)          // 640000 float2 = 5,120,000 B
#define M2_BYTE_OFF (S1_FLOAT2S * 8)     // 16B-aligned

#define GLOBAL_AS __attribute__((address_space(1)))
#define SHARED_AS __attribute__((address_space(3)))

// INVOLUTIVE swizzle (bits 3,4,5 XOR into 0,1,2; disjoint => sz(sz(F))=F).
__device__ __forceinline__ int sz16(int F) { return F ^ ((F >> 3) & 7); }
__device__ __forceinline__ float clip1f(float v) { return fminf(fmaxf(v, -1.0f), 1.0f); }

// ---------------------------------------------------------------------------
// pass_a1: per (row, 32-chunk) LOCAL stage-1 end state (zero y-init, true
// x-history). FIR f32, y-recurrence f64; e1 stored f32.
// Threads g<2 also emit M16 = A2stage^16 and powers M^2, M^3 per filter.
// ---------------------------------------------------------------------------
__global__ __launch_bounds__(256) void pass_a1(const float* __restrict__ x,
                                               const float* __restrict__ nn,
                                               float2* __restrict__ e1,
                                               const float* __restrict__ cx,
                                               const float* __restrict__ cn,
                                               float4* __restrict__ m2) {
  int g = blockIdx.x * blockDim.x + threadIdx.x;
  if (g < 2) {
    const float* c = g ? cn : cx;
    const float A1c = c[0], A2c = c[1];
    float pm2 = 0.f, pm1 = 0.f, p0 = 1.f;
#pragma unroll
    for (int k = 0; k < 16; ++k) {
      float pn = -A1c * p0 - A2c * pm1;
      pm2 = pm1; pm1 = p0; p0 = pn;
    }
    float m00 = p0, m01 = -A2c * pm1, m10 = pm1, m11 = -A2c * pm2;
    float q00 = m00*m00 + m01*m10, q01 = m00*m01 + m01*m11;
    float q10 = m10*m00 + m11*m10, q11 = m10*m01 + m11*m11;       // M^2
    float r00 = q00*m00 + q01*m10, r01 = q00*m01 + q01*m11;
    float r10 = q10*m00 + q11*m10, r11 = q10*m01 + q11*m11;       // M^3
    m2[g*3 + 0] = make_float4(m00, m01, m10, m11);
    m2[g*3 + 1] = make_float4(q00, q01, q10, q11);
    m2[g*3 + 2] = make_float4(r00, r01, r10, r11);
  }
  if (g >= NROW * NCH) return;
  int row = g / NCH, c = g % NCH;
  const float* src = (row < 64) ? (x + (size_t)row * T_LEN)
                                : (nn + (size_t)(row - 64) * T_LEN);
  const float* xp = src + c * CH;
  float x1 = 0.f, x2 = 0.f;
  if (c) { x1 = xp[-1]; x2 = xp[-2]; }
  double y1 = 0.0, y2 = 0.0;
#pragma unroll
  for (int j = 0; j < CH; j += 4) {
    float4 xv = *reinterpret_cast<const float4*>(xp + j);
#define A1STEP(XF) { float xt = (XF); \
    float fir = (xt - 2.f * x1 + x2); \
    double y = fma(C1_HP, y1, fma(C2_HP, y2, (double)fir)); \
    x2 = x1; x1 = xt; y2 = y1; y1 = y; }
    A1STEP(xv.x) A1STEP(xv.y) A1STEP(xv.z) A1STEP(xv.w)
#undef A1STEP
  }
  e1[g] = make_float2((float)y1, (float)y2);
}

// ---------------------------------------------------------------------------
// scan_row: one block (4 waves) per row; affine Kogge-Stone over 32-chunk
// maps (f64 internal, f32 e-inputs); emits exact chunk-start states (f32).
// ---------------------------------------------------------------------------
__global__ __launch_bounds__(256) void scan_row(const float2* __restrict__ e,
                                                float2* __restrict__ s) {
  __shared__ double wm[4][6];
  const int t = threadIdx.x, row = blockIdx.x;
  const int lane = t & 63, wv = t >> 6;
  double pm2 = 0.0, pm1 = 0.0, p0 = 1.0;
#pragma unroll
  for (int k = 1; k <= CH; ++k) {
    double pn = C1_HP * p0 + C2_HP * pm1;
    pm2 = pm1; pm1 = p0; p0 = pn;
  }
  const double m00 = p0,  m01 = C2_HP * pm1;
  const double m10 = pm1, m11 = C2_HP * pm2;
  const float2* ep = e + (size_t)row * NCH;
  const int base = t * OWNT;
  double f1 = 0.0, f2 = 0.0;
  for (int j = 0; j < OWNT; ++j) {
    int c = base + j;
    float2 ev = (c < NCH) ? ep[c] : make_float2(0.f, 0.f);
    double n1 = m00 * f1 + m01 * f2 + (double)ev.x;
    double n2 = m10 * f1 + m11 * f2 + (double)ev.y;
    f1 = n1; f2 = n2;
  }
  double b00 = m00, b01 = m01, b10 = m10, b11 = m11;
  double r00 = 1.0, r01 = 0.0, r10 = 0.0, r11 = 1.0;
  int ee = OWNT;
  while (ee) {
    if (ee & 1) {
      double t00 = b00 * r00 + b01 * r10, t01 = b00 * r01 + b01 * r11;
      double t10 = b10 * r00 + b11 * r10, t11 = b10 * r01 + b11 * r11;
      r00 = t00; r01 = t01; r10 = t10; r11 = t11;
    }
    double q00 = b00 * b00 + b01 * b10, q01 = b00 * b01 + b01 * b11;
    double q10 = b10 * b00 + b11 * b10, q11 = b10 * b01 + b11 * b11;
    b00 = q00; b01 = q01; b10 = q10; b11 = q11;
    ee >>= 1;
  }
  double P00 = r00, P01 = r01, P10 = r10, P11 = r11, V1 = f1, V2 = f2;
#pragma unroll
  for (int off = 1; off < 64; off <<= 1) {
    double u00 = __shfl_up(P00, off), u01 = __shfl_up(P01, off);
    double u10 = __shfl_up(P10, off), u11 = __shfl_up(P11, off);
    double uv1 = __shfl_up(V1, off),  uv2 = __shfl_up(V2, off);
    if (lane >= off) {
      double nv1 = P00 * uv1 + P01 * uv2 + V1;
      double nv2 = P10 * uv1 + P11 * uv2 + V2;
      double n00 = P00 * u00 + P01 * u10, n01 = P00 * u01 + P01 * u11;
      double n10 = P10 * u00 + P11 * u10, n11 = P10 * u01 + P11 * u11;
      P00 = n00; P01 = n01; P10 = n10; P11 = n11; V1 = nv1; V2 = nv2;
    }
  }
  if (lane == 63) {
    wm[wv][0] = P00; wm[wv][1] = P01; wm[wv][2] = P10; wm[wv][3] = P11;
    wm[wv][4] = V1;  wm[wv][5] = V2;
  }
  __syncthreads();
  double S1 = 0.0, S2 = 0.0;
  for (int w = 0; w < wv; ++w) {
    double n1 = wm[w][0] * S1 + wm[w][1] * S2 + wm[w][4];
    double n2 = wm[w][2] * S1 + wm[w][3] * S2 + wm[w][5];
    S1 = n1; S2 = n2;
  }
  double q00 = __shfl_up(P00, 1), q01 = __shfl_up(P01, 1);
  double q10 = __shfl_up(P10, 1), q11 = __shfl_up(P11, 1);
  double qv1 = __shfl_up(V1, 1),  qv2 = __shfl_up(V2, 1);
  double st1, st2;
  if (lane == 0) { st1 = S1; st2 = S2; }
  else { st1 = q00 * S1 + q01 * S2 + qv1; st2 = q10 * S1 + q11 * S2 + qv2; }
  float2* sp = s + (size_t)row * NCH;
  double s1v = st1, s2v = st2;
  for (int j = 0; j < OWNT; ++j) {
    int c = base + j;
    if (c < NCH) {
      sp[c] = make_float2((float)s1v, (float)s2v);
      float2 ev = ep[c];
      double n1 = m00 * s1v + m01 * s2v + (double)ev.x;
      double n2 = m10 * s1v + m11 * s2v + (double)ev.y;
      s1v = n1; s2v = n2;
    }
  }
}

// macros shared by the emit tile body
#define ABSTEP(REF) { \
    float yy = fmaf(C1F, y1, fmaf(C2F, y2, (REF))); \
    float vv = clip1f(yy); \
    float zz = fmaf(-A1c, z1, fmaf(-A2c, z2, fmaf(B2c, v2, fmaf(B1c, v1, vv)))); \
    y2 = y1; y1 = yy; v2 = v1; v1 = vv; z2 = z1; z1 = zz; REF = zz; }
#define CSSTEP(ZB, OT) { float hh = fmaf(-A1c, h1, -A2c * h2); \
    OT = clip1f((ZB) + hh); h2 = h1; h1 = hh; }
#define ADVSTEP(XT) { float xt_ = (XT); \
    float fir = (xt_ - 2.f * ax1 + ax2); \
    float yy = fmaf(C1F, y1, fmaf(C2F, y2, fir)); \
    ax2 = ax1; ax1 = xt_; y2 = y1; y1 = yy; }

// ---------------------------------------------------------------------------
// emit: TWO 64-chunk tiles per wave (8 KB/wave, 32 KB/block, 5 blocks/CU),
// 2-deep counted-vmcnt pipeline: all global seed loads first, then 4+4 async
// global_load_lds, vmcnt(4) -> compute+store T0 (T1 loads in flight),
// vmcnt(4) -> compute+store T1. Boundary tiles: manual path. ZERO barriers.
// ---------------------------------------------------------------------------
__global__ __launch_bounds__(256, 5) void emit_kernel(const float* __restrict__ x,
                                                      const float* __restrict__ nn,
                                                      const float2* __restrict__ s1,
                                                      const float* __restrict__ cx,
                                                      const float* __restrict__ cn,
                                                      const float4* __restrict__ m2,
                                                      float* __restrict__ out) {
  __shared__ float4 ws4[2048];                 // 4 waves x 2 tiles x 256 f4
  const int tid = threadIdx.x, lane = tid & 63, wv = tid >> 6;
  const int b = blockIdx.x;
  const int row = b / TILES16, tile = b % TILES16;
  const int W0a = tile * B16 + wv * WAVE_OWN;  // tile0 first own chunk
  const int W0b = W0a + OWN16;                 // tile1 first own chunk
  const float* src = (row < 64) ? x + (size_t)row * T_LEN
                                : nn + (size_t)(row - 64) * T_LEN;
  const float4* src4 = reinterpret_cast<const float4*>(src);
  const float2* srow = s1 + (size_t)row * NCH;
  const float* cf = (row < 64) ? cx : cn;
  const float A1c = cf[0], A2c = cf[1], B1c = cf[2], B2c = cf[3];
  const int fi = (row < 64) ? 0 : 1;
  const float4 M1q = m2[fi*3], M2q = m2[fi*3+1], M3q = m2[fi*3+2];

  const int ca = W0a - 4 + lane, cb = W0b - 4 + lane;
  const bool okA = (ca >= 0) && (ca < NCH16);
  const bool okB = (cb >= 0) && (cb < NCH16);
  const long b4a = (long)(W0a - 4) * 4, b4b = (long)(W0b - 4) * 4;
  const int WOFFa = wv * 512, WOFFb = wv * 512 + 256;
  const bool intA = (b4a >= 0) && (b4a + 256 <= ROW4);
  const bool intB = (b4b >= 0) && (b4b + 256 <= ROW4);

  // ---- ALL global seed loads FIRST (oldest in vmcnt queue) ----
  float2 svA = make_float2(0.f, 0.f), svB = make_float2(0.f, 0.f);
  if (okA && ca > 0) svA = srow[ca >> 1];
  if (okB && cb > 0) svB = srow[cb >> 1];
  float2 tpA = make_float2(0.f, 0.f), tqA = make_float2(0.f, 0.f);
  float2 tpB = make_float2(0.f, 0.f), tqB = make_float2(0.f, 0.f);
  if (lane == 0) {
    if (okA && ca > 0) tpA = *reinterpret_cast<const float2*>(src + (long)ca * 16 - 2);
    if (okB && cb > 0) tpB = *reinterpret_cast<const float2*>(src + (long)cb * 16 - 2);
  }
  if (lane == 1) {
    if (okA && ca >= 2) tqA = *reinterpret_cast<const float2*>(src + (long)(ca - 1) * 16 - 2);
    if (okB && cb >= 2) tqB = *reinterpret_cast<const float2*>(src + (long)(cb - 1) * 16 - 2);
  }

  // ---- per-tile body (round-16 verified machinery) ----
  auto process = [&](int c, bool cOK, long base4, int WOFF,
                     float2 sv, float2 tp, float2 tq) {
    float4 a[4];
#pragma unroll
    for (int q = 0; q < 4; ++q) a[q] = ws4[WOFF + sz16(lane * 4 + q)];
    float tx  = __shfl_up(a[3].w, 1), ty  = __shfl_up(a[3].z, 1);
    float t2x = __shfl_up(a[3].w, 2), t2y = __shfl_up(a[3].z, 2);
    float x1 = 0.f, x2 = 0.f, y1 = 0.f, y2 = 0.f, v1 = 0.f, v2 = 0.f;
    if (cOK && c > 0) {
      y1 = sv.x; y2 = sv.y;
      if ((lane & 1) == 0) {
        if (lane == 0) { x2 = tp.x; x1 = tp.y; }
        else { x1 = tx; x2 = ty; }
      } else {
        float ax1 = 0.f, ax2 = 0.f;
        if (lane == 1) { if (c >= 2) { ax2 = tq.x; ax1 = tq.y; } }
        else { ax1 = t2x; ax2 = t2y; }
        float4 p0 = ws4[WOFF + sz16((lane - 1) * 4 + 0)];
        float4 p1 = ws4[WOFF + sz16((lane - 1) * 4 + 1)];
        float4 p2 = ws4[WOFF + sz16((lane - 1) * 4 + 2)];
        float4 p3 = ws4[WOFF + sz16((lane - 1) * 4 + 3)];
        ADVSTEP(p0.x) ADVSTEP(p0.y) ADVSTEP(p0.z) ADVSTEP(p0.w)
        ADVSTEP(p1.x) ADVSTEP(p1.y) ADVSTEP(p1.z) ADVSTEP(p1.w)
        ADVSTEP(p2.x) ADVSTEP(p2.y) ADVSTEP(p2.z) ADVSTEP(p2.w)
        ADVSTEP(p3.x) ADVSTEP(p3.y) ADVSTEP(p3.z) ADVSTEP(p3.w)
        x1 = ax1; x2 = ax2;
      }
      v1 = clip1f(y1); v2 = clip1f(y2);
    }
    // FIR precompute (input-only)
    {
      float xp1 = x1, xp2 = x2;
#pragma unroll
      for (int q = 0; q < 4; ++q) {
        float4 t = a[q];
        float4 f;
        f.x = t.x - 2.f * xp1 + xp2;
        f.y = t.y - 2.f * t.x + xp1;
        f.z = t.z - 2.f * t.y + t.x;
        f.w = t.w - 2.f * t.z + t.y;
        xp2 = t.z; xp1 = t.w;
        a[q] = f;
      }
    }
    float z1 = 0.f, z2 = 0.f;
    if (cOK) {
#pragma unroll
      for (int q = 0; q < 4; ++q) {
        ABSTEP(a[q].x) ABSTEP(a[q].y) ABSTEP(a[q].z) ABSTEP(a[q].w)
      }
    }
    float u1x = __shfl_up(z1, 1), u1y = __shfl_up(z2, 1);
    float u2x = __shfl_up(z1, 2), u2y = __shfl_up(z2, 2);
    float u3x = __shfl_up(z1, 3), u3y = __shfl_up(z2, 3);
    float u4x = __shfl_up(z1, 4), u4y = __shfl_up(z2, 4);
    if (lane >= 4 && cOK) {
      float s2x = 0.f, s2y = 0.f;
      if (c >= 1) { s2x = u1x; s2y = u1y; }
      if (c >= 2) { s2x = fmaf(M1q.x, u2x, fmaf(M1q.y, u2y, s2x));
                    s2y = fmaf(M1q.z, u2x, fmaf(M1q.w, u2y, s2y)); }
      if (c >= 3) { s2x = fmaf(M2q.x, u3x, fmaf(M2q.y, u3y, s2x));
                    s2y = fmaf(M2q.z, u3x, fmaf(M2q.w, u3y, s2y)); }
      if (c >= 4) { s2x = fmaf(M3q.x, u4x, fmaf(M3q.y, u4y, s2x));
                    s2y = fmaf(M3q.z, u4x, fmaf(M3q.w, u4y, s2y)); }
      float h1 = s2x, h2 = s2y;
#pragma unroll
      for (int q = 0; q < 4; ++q) {
        float4 o;
        CSSTEP(a[q].x, o.x) CSSTEP(a[q].y, o.y)
        CSSTEP(a[q].z, o.z) CSSTEP(a[q].w, o.w)
        ws4[WOFF + sz16(lane * 4 + q)] = o;
      }
    }
    float* orow = out + (size_t)row * T_LEN;
#pragma unroll
    for (int q = 0; q < 4; ++q) {
      int f = q * 64 + lane;
      long g4 = base4 + f;
      if (f >= 16 && g4 < ROW4)
        reinterpret_cast<float4*>(orow)[g4] = ws4[WOFF + sz16(f)];
    }
  };

  if (intA && intB) {
    // ---- 2-deep pipeline ----
    const int lane_sz = lane ^ ((lane >> 3) & 7);
#pragma unroll
    for (int q = 0; q < 4; ++q)
      __builtin_amdgcn_global_load_lds(
          (const GLOBAL_AS void*)(src4 + b4a + q * 64 + lane_sz),
          (SHARED_AS void*)(ws4 + WOFFa + q * 64), 16, 0, 0);
#pragma unroll
    for (int q = 0; q < 4; ++q)
      __builtin_amdgcn_global_load_lds(
          (const GLOBAL_AS void*)(src4 + b4b + q * 64 + lane_sz),
          (SHARED_AS void*)(ws4 + WOFFb + q * 64), 16, 0, 0);
    asm volatile("s_waitcnt vmcnt(4)" ::: "memory");   // T0 staged; T1 in flight
    process(ca, okA, b4a, WOFFa, svA, tpA, tqA);
    asm volatile("s_waitcnt vmcnt(4)" ::: "memory");   // T1 staged; T0 stores may remain
    process(cb, okB, b4b, WOFFb, svB, tpB, tqB);
  } else {
    // ---- boundary path: manual bounds-checked staging per tile ----
#pragma unroll
    for (int q = 0; q < 4; ++q) {
      int f = q * 64 + lane;
      long g4 = b4a + f;
      float4 v = make_float4(0.f, 0.f, 0.f, 0.f);
      if (g4 >= 0 && g4 < ROW4) v = src4[g4];
      ws4[WOFFa + sz16(f)] = v;
    }
    process(ca, okA, b4a, WOFFa, svA, tpA, tqA);
#pragma unroll
    for (int q = 0; q < 4; ++q) {
      int f = q * 64 + lane;
      long g4 = b4b + f;
      float4 v = make_float4(0.f, 0.f, 0.f, 0.f);
      if (g4 >= 0 && g4 < ROW4) v = src4[g4];
      ws4[WOFFb + sz16(f)] = v;
    }
    process(cb, okB, b4b, WOFFb, svB, tpB, tqB);
  }
}

#undef ABSTEP
#undef CSSTEP
#undef ADVSTEP

// ---------------------------------------------------------------------------
extern "C" void kernel_launch(void* const* d_in, const int* in_sizes, int n_in,
                              void* d_out, int out_size, void* d_ws, size_t ws_size,
                              hipStream_t stream) {
  const float* x  = (const float*)d_in[0];   // (64, 160000)
  const float* nn = (const float*)d_in[1];   // (64, 160000)
  const float* cx = (const float*)d_in[2];   // (4,) a1,a2,b1,b2
  const float* cn = (const float*)d_in[3];   // (4,)
  float* out = (float*)d_out;                // (128, 160000) flat

  // e1 (f32, 5.12 MB) aliases d_out: written by pass_a1, consumed by
  // scan_row, then fully overwritten by emit. s1 + m2 (96 B) in ws.
  float2* e1 = (float2*)d_out;
  float2* s1 = (float2*)d_ws;
  float4* m2 = (float4*)((char*)d_ws + M2_BYTE_OFF);

  const int total = NROW * NCH;              // 640000
  const int blk = 256;
  const int nb = (total + blk - 1) / blk;    // 2500

  pass_a1<<<nb, blk, 0, stream>>>(x, nn, e1, cx, cn, m2);
  scan_row<<<NROW, blk, 0, stream>>>(e1, s1);
  emit_kernel<<<NBLK16, blk, 0, stream>>>(x, nn, s1, cx, cn, m2, out);
}